// Round 1
// baseline (275.998 us; speedup 1.0000x reference)
//
#include <hip/hip_runtime.h>
#include <hip/hip_bf16.h>

#define D 512
#define NSEQ 2048
#define NB 8
#define QBLK 32
#define KVBLK 64
#define NTHREADS 512
#define ROWP (D + 8)        // padded row length (bf16 elems) for Qs/Bs
#define SROWP (KVBLK + 4)   // padded row length (f32) for Ss
#define PROWP (KVBLK + 8)   // padded row length (bf16) for Ps

typedef __attribute__((ext_vector_type(8))) short bf16x8;
typedef __attribute__((ext_vector_type(4))) float f32x4;
typedef __attribute__((ext_vector_type(4))) unsigned short u16x4;

static __device__ __forceinline__ unsigned short f2b(float f) {
  unsigned u = __builtin_bit_cast(unsigned, f);
  return (unsigned short)((u + 0x7FFFu + ((u >> 16) & 1u)) >> 16);
}

__global__ __launch_bounds__(NTHREADS, 2)
void attn_fused(const float* __restrict__ A, const float* __restrict__ Bm,
                float* __restrict__ Out) {
  __shared__ unsigned short Qs[QBLK * ROWP];
  __shared__ unsigned short Bs[KVBLK * ROWP];
  __shared__ float Ss[QBLK * SROWP];
  __shared__ unsigned short Ps[QBLK * PROWP];
  __shared__ float mS[QBLK];
  __shared__ float lS[QBLK];
  __shared__ float aS[QBLK];

  const int tid  = threadIdx.x;
  const int wid  = tid >> 6;
  const int lane = tid & 63;
  const int l16  = lane & 15;
  const int g4   = lane >> 4;

  const int batch = blockIdx.x & 7;         // batch -> XCD (L2 locality for b)
  const int qt    = blockIdx.x >> 3;
  const int qbase = qt * QBLK;

  const float* Ab = A   + (size_t)batch * NSEQ * D;
  const float* Bb = Bm  + (size_t)batch * NSEQ * D;
  float*       Ob = Out + (size_t)batch * NSEQ * D;

  const float scale = 0.04419417382415922f;  // 1/sqrt(512)

  // ---- stage Q (pre-scaled by 1/sqrt(D)), 32x512 fp32 -> bf16 ----
  #pragma unroll
  for (int it = 0; it < (QBLK * D) / (NTHREADS * 4); ++it) {   // 8 iters
    int flat = it * (NTHREADS * 4) + tid * 4;
    int row = flat >> 9;          // /512
    int col = flat & (D - 1);
    float4 v = *reinterpret_cast<const float4*>(Ab + (size_t)(qbase + row) * D + col);
    u16x4 h = { f2b(v.x * scale), f2b(v.y * scale), f2b(v.z * scale), f2b(v.w * scale) };
    *reinterpret_cast<u16x4*>(&Qs[row * ROWP + col]) = h;
  }
  if (tid < QBLK) { mS[tid] = -1e30f; lS[tid] = 0.f; }

  f32x4 acc[2][4];
  #pragma unroll
  for (int mi = 0; mi < 2; ++mi)
    #pragma unroll
    for (int ni = 0; ni < 4; ++ni)
      acc[mi][ni] = (f32x4){0.f, 0.f, 0.f, 0.f};

  const int qi = wid >> 2;   // wave's q 16-tile (0..1) for QK^T
  const int ki = wid & 3;    // wave's kv 16-tile (0..3) for QK^T

  for (int kt = 0; kt < NSEQ / KVBLK; ++kt) {
    __syncthreads();   // prev PV done with Bs; Qs/stats visible on kt==0

    // ---- stage B tile 64x512 fp32 -> bf16 ----
    const float* Bt = Bb + (size_t)kt * KVBLK * D;
    #pragma unroll
    for (int it = 0; it < (KVBLK * D) / (NTHREADS * 4); ++it) { // 16 iters
      int flat = it * (NTHREADS * 4) + tid * 4;
      int row = flat >> 9;
      int col = flat & (D - 1);
      float4 v = *reinterpret_cast<const float4*>(Bt + (size_t)row * D + col);
      u16x4 h = { f2b(v.x), f2b(v.y), f2b(v.z), f2b(v.w) };
      *reinterpret_cast<u16x4*>(&Bs[row * ROWP + col]) = h;
    }
    __syncthreads();

    // ---- QK^T: each wave one 16x16 S-tile, K = 512 ----
    f32x4 s = {0.f, 0.f, 0.f, 0.f};
    #pragma unroll
    for (int ks = 0; ks < D / 32; ++ks) {
      bf16x8 af = *reinterpret_cast<const bf16x8*>(&Qs[(qi * 16 + l16) * ROWP + ks * 32 + g4 * 8]);
      bf16x8 bf = *reinterpret_cast<const bf16x8*>(&Bs[(ki * 16 + l16) * ROWP + ks * 32 + g4 * 8]);
      s = __builtin_amdgcn_mfma_f32_16x16x32_bf16(af, bf, s, 0, 0, 0);
    }
    // C layout: col = lane&15 (kv), row = (lane>>4)*4 + r (q)
    #pragma unroll
    for (int r = 0; r < 4; ++r)
      Ss[(qi * 16 + g4 * 4 + r) * SROWP + ki * 16 + l16] = s[r];
    __syncthreads();

    // ---- online softmax: wave w owns rows 4w..4w+3; 16 lanes per row ----
    {
      int row = wid * 4 + g4;
      float sv[4];
      float mloc = -1e30f;
      #pragma unroll
      for (int j = 0; j < 4; ++j) {
        sv[j] = Ss[row * SROWP + l16 + 16 * j];
        mloc = fmaxf(mloc, sv[j]);
      }
      #pragma unroll
      for (int off = 1; off < 16; off <<= 1)
        mloc = fmaxf(mloc, __shfl_xor(mloc, off));
      float mold = mS[row];
      float mnew = fmaxf(mold, mloc);
      float al = __expf(mold - mnew);
      float psum = 0.f;
      #pragma unroll
      for (int j = 0; j < 4; ++j) {
        float p = __expf(sv[j] - mnew);
        psum += p;
        Ps[row * PROWP + l16 + 16 * j] = f2b(p);
      }
      #pragma unroll
      for (int off = 1; off < 16; off <<= 1)
        psum += __shfl_xor(psum, off);
      if (l16 == 0) {
        mS[row] = mnew;
        lS[row] = lS[row] * al + psum;
        aS[row] = al;
      }
    }
    __syncthreads();

    // ---- rescale acc + PV: wave owns d-slice [wid*64, wid*64+64) ----
    float alv[2][4];
    #pragma unroll
    for (int mi = 0; mi < 2; ++mi)
      #pragma unroll
      for (int r = 0; r < 4; ++r)
        alv[mi][r] = aS[mi * 16 + g4 * 4 + r];
    #pragma unroll
    for (int mi = 0; mi < 2; ++mi)
      #pragma unroll
      for (int ni = 0; ni < 4; ++ni)
        #pragma unroll
        for (int r = 0; r < 4; ++r)
          acc[mi][ni][r] *= alv[mi][r];

    #pragma unroll
    for (int ks = 0; ks < KVBLK / 32; ++ks) {
      bf16x8 pf[2];
      #pragma unroll
      for (int mi = 0; mi < 2; ++mi)
        pf[mi] = *reinterpret_cast<const bf16x8*>(&Ps[(mi * 16 + l16) * PROWP + ks * 32 + g4 * 8]);
      #pragma unroll
      for (int ni = 0; ni < 4; ++ni) {
        int dcol = wid * 64 + ni * 16 + l16;
        bf16x8 vv;
        #pragma unroll
        for (int j = 0; j < 8; ++j)
          vv[j] = (short)Bs[(ks * 32 + g4 * 8 + j) * ROWP + dcol];  // V column gather
        #pragma unroll
        for (int mi = 0; mi < 2; ++mi)
          acc[mi][ni] = __builtin_amdgcn_mfma_f32_16x16x32_bf16(pf[mi], vv, acc[mi][ni], 0, 0, 0);
      }
    }
  }

  // ---- epilogue: out = acc / l + a ----
  float rl[2][4];
  #pragma unroll
  for (int mi = 0; mi < 2; ++mi)
    #pragma unroll
    for (int r = 0; r < 4; ++r)
      rl[mi][r] = 1.0f / lS[mi * 16 + g4 * 4 + r];
  #pragma unroll
  for (int mi = 0; mi < 2; ++mi)
    #pragma unroll
    for (int ni = 0; ni < 4; ++ni)
      #pragma unroll
      for (int r = 0; r < 4; ++r) {
        int q = qbase + mi * 16 + g4 * 4 + r;
        int d = wid * 64 + ni * 16 + l16;
        size_t off = (size_t)q * D + d;
        Ob[off] = acc[mi][ni][r] * rl[mi][r] + Ab[off];
      }
}

extern "C" void kernel_launch(void* const* d_in, const int* in_sizes, int n_in,
                              void* d_out, int out_size, void* d_ws, size_t ws_size,
                              hipStream_t stream) {
  const float* a = (const float*)d_in[0];
  const float* b = (const float*)d_in[1];
  float* out = (float*)d_out;
  dim3 grid(NB * (NSEQ / QBLK));
  dim3 block(NTHREADS);
  attn_fused<<<grid, block, 0, stream>>>(a, b, out);
}

// Round 3
// 217.324 us; speedup vs baseline: 1.2700x; 1.2700x over previous
//
#include <hip/hip_runtime.h>
#include <hip/hip_bf16.h>

#define D 512
#define NSEQ 2048
#define NB 8
#define QBLK 32
#define KVBLK 64
#define NTHREADS 512
#define NT (NSEQ / KVBLK)          // 32 kv tiles
#define ROWE 2056                  // elems per kv-group row: 4096B data + 16B pad
#define BUFE (16 * ROWE)           // 32896 elems per buffer
#define SROWP (KVBLK + 4)          // f32 row for Ss
#define PROWP (KVBLK + 8)          // bf16 row for Ps

typedef __attribute__((ext_vector_type(8))) short bf16x8;
typedef __attribute__((ext_vector_type(4))) float f32x4;

static __device__ __forceinline__ unsigned short f2b(float f) {
  unsigned u = __builtin_bit_cast(unsigned, f);
  return (unsigned short)((u + 0x7FFFu + ((u >> 16) & 1u)) >> 16);
}

// fp32 -> bf16 pre-convert of B (memory-bound, ~10us)
__global__ __launch_bounds__(256) void conv_b16(const float* __restrict__ in,
                                                unsigned short* __restrict__ out) {
  size_t i = ((size_t)blockIdx.x * 256 + threadIdx.x) * 8;
  float4 v0 = *reinterpret_cast<const float4*>(in + i);
  float4 v1 = *reinterpret_cast<const float4*>(in + i + 4);
  bf16x8 h;
  h[0] = (short)f2b(v0.x); h[1] = (short)f2b(v0.y);
  h[2] = (short)f2b(v0.z); h[3] = (short)f2b(v0.w);
  h[4] = (short)f2b(v1.x); h[5] = (short)f2b(v1.y);
  h[6] = (short)f2b(v1.z); h[7] = (short)f2b(v1.w);
  *reinterpret_cast<bf16x8*>(out + i) = h;
}

// LDS element offset of B element (kv, d) inside one buffer:
//   (kv>>2)*ROWE + (d>>4)*64 + (kv&3)*16 + (d&15)
// Bank math for the V-gather (fixed j): bank = K0 + 8*g4 + (l16>>1) mod 32
//   -> all 32 banks, 2 lanes per aligned dword (broadcast) = conflict-free.
template<bool PRE>
__global__ __launch_bounds__(NTHREADS, 2)
void attn_fused(const float* __restrict__ A, const float* __restrict__ B32,
                const unsigned short* __restrict__ B16, float* __restrict__ Out) {
  __shared__ __align__(16) unsigned short Bs[2][BUFE];   // 131584 B, double-buffered
  __shared__ float Ss[QBLK * SROWP];
  __shared__ unsigned short Ps[QBLK * PROWP];
  __shared__ float mS[QBLK];
  __shared__ float lS[QBLK];
  __shared__ float aS[QBLK];

  const int tid  = threadIdx.x;
  const int wid  = tid >> 6;
  const int lane = tid & 63;
  const int l16  = lane & 15;
  const int g4   = lane >> 4;

  const int batch = blockIdx.x & 7;       // batch -> XCD (L2 locality for b panel)
  const int qt    = blockIdx.x >> 3;
  const int qbase = qt * QBLK;

  const float*          Ab   = A   + (size_t)batch * NSEQ * D;
  const float*          Bb32 = B32 + (size_t)batch * NSEQ * D;
  const unsigned short* Bb16 = PRE ? (B16 + (size_t)batch * NSEQ * D) : nullptr;
  float*                Ob   = Out + (size_t)batch * NSEQ * D;

  const float scale = 0.04419417382415922f;  // 1/sqrt(512)

  const int qi = wid >> 2;   // wave's q 16-tile for QK^T
  const int ki = wid & 3;    // wave's kv 16-tile for QK^T

  // ---- Q tile into registers (pre-scaled), 16 frags x 8 bf16 ----
  const int qrow = qbase + qi * 16 + l16;
  const float* Arow = Ab + (size_t)qrow * D;
  bf16x8 qf[16];
  #pragma unroll
  for (int ks = 0; ks < 16; ++ks) {
    int d0 = ks * 32 + g4 * 8;
    float4 v0 = *reinterpret_cast<const float4*>(Arow + d0);
    float4 v1 = *reinterpret_cast<const float4*>(Arow + d0 + 4);
    bf16x8 f;
    f[0] = (short)f2b(v0.x * scale); f[1] = (short)f2b(v0.y * scale);
    f[2] = (short)f2b(v0.z * scale); f[3] = (short)f2b(v0.w * scale);
    f[4] = (short)f2b(v1.x * scale); f[5] = (short)f2b(v1.y * scale);
    f[6] = (short)f2b(v1.z * scale); f[7] = (short)f2b(v1.w * scale);
    qf[ks] = f;
  }
  if (tid < QBLK) { mS[tid] = -1e30f; lS[tid] = 0.f; }

  f32x4 acc[2][4];
  #pragma unroll
  for (int mi = 0; mi < 2; ++mi)
    #pragma unroll
    for (int ni = 0; ni < 4; ++ni)
      acc[mi][ni] = (f32x4){0.f, 0.f, 0.f, 0.f};

  // ---- prologue: DMA tile 0 into buffer 0 ----
  if constexpr (PRE) {
    #pragma unroll
    for (int c = 0; c < 8; ++c) {
      int id = wid * 8 + c;
      int g = id >> 2, q = id & 3;
      const unsigned short* src = Bb16
          + (size_t)(g * 4 + ((lane >> 1) & 3)) * D
          + q * 128 + (lane >> 3) * 16 + (lane & 1) * 8;
      unsigned short* dst = &Bs[0][g * ROWE + q * 512];
      __builtin_amdgcn_global_load_lds(
          (const __attribute__((address_space(1))) void*)src,
          (__attribute__((address_space(3))) void*)dst, 16, 0, 0);
    }
  }

  for (int kt = 0; kt < NT; ++kt) {
    const int cur = PRE ? (kt & 1) : 0;

    if constexpr (PRE) {
      asm volatile("s_waitcnt vmcnt(0)" ::: "memory");   // DMA for tile kt landed
      __builtin_amdgcn_s_barrier();                      // all waves' DMA done; prev-tile reads done
      if (kt + 1 < NT) {
        const unsigned short* Bt = Bb16 + (size_t)(kt + 1) * KVBLK * D;
        #pragma unroll
        for (int c = 0; c < 8; ++c) {
          int id = wid * 8 + c;
          int g = id >> 2, q = id & 3;
          const unsigned short* src = Bt
              + (size_t)(g * 4 + ((lane >> 1) & 3)) * D
              + q * 128 + (lane >> 3) * 16 + (lane & 1) * 8;
          unsigned short* dst = &Bs[cur ^ 1][g * ROWE + q * 512];
          __builtin_amdgcn_global_load_lds(
              (const __attribute__((address_space(1))) void*)src,
              (__attribute__((address_space(3))) void*)dst, 16, 0, 0);
        }
      }
    } else {
      __builtin_amdgcn_s_barrier();                      // prev iteration reads done
      const float* Bt = Bb32 + (size_t)kt * KVBLK * D;
      #pragma unroll
      for (int c = 0; c < 8; ++c) {
        int id = wid * 8 + c;
        int g = id >> 2, q = id & 3;
        int kv = g * 4 + ((lane >> 1) & 3);
        int d  = q * 128 + (lane >> 3) * 16 + (lane & 1) * 8;
        const float* s = Bt + (size_t)kv * D + d;
        float4 v0 = *reinterpret_cast<const float4*>(s);
        float4 v1 = *reinterpret_cast<const float4*>(s + 4);
        bf16x8 h;
        h[0] = (short)f2b(v0.x); h[1] = (short)f2b(v0.y);
        h[2] = (short)f2b(v0.z); h[3] = (short)f2b(v0.w);
        h[4] = (short)f2b(v1.x); h[5] = (short)f2b(v1.y);
        h[6] = (short)f2b(v1.z); h[7] = (short)f2b(v1.w);
        *reinterpret_cast<bf16x8*>(&Bs[0][g * ROWE + q * 512 + lane * 8]) = h;
      }
      asm volatile("s_waitcnt lgkmcnt(0)" ::: "memory");
      __builtin_amdgcn_s_barrier();
    }

    // ---- QK^T: wave (qi,ki), Q from regs, B via b128 from subtiled LDS ----
    {
      f32x4 s = {0.f, 0.f, 0.f, 0.f};
      const int bbase = (ki * 4 + (l16 >> 2)) * ROWE + (l16 & 3) * 16 + (g4 & 1) * 8;
      __builtin_amdgcn_s_setprio(1);
      #pragma unroll
      for (int ks = 0; ks < 16; ++ks) {
        const bf16x8 bf = *reinterpret_cast<const bf16x8*>(
            &Bs[cur][bbase + (ks * 2 + (g4 >> 1)) * 64]);
        s = __builtin_amdgcn_mfma_f32_16x16x32_bf16(qf[ks], bf, s, 0, 0, 0);
      }
      __builtin_amdgcn_s_setprio(0);
      #pragma unroll
      for (int r = 0; r < 4; ++r)
        Ss[(qi * 16 + g4 * 4 + r) * SROWP + ki * 16 + l16] = s[r];
    }
    asm volatile("s_waitcnt lgkmcnt(0)" ::: "memory");
    __builtin_amdgcn_s_barrier();

    // ---- online softmax: wave w owns rows 4w..4w+3 ----
    {
      int row = wid * 4 + g4;
      float sv[4];
      float mloc = -1e30f;
      #pragma unroll
      for (int j = 0; j < 4; ++j) {
        sv[j] = Ss[row * SROWP + l16 + 16 * j];
        mloc = fmaxf(mloc, sv[j]);
      }
      #pragma unroll
      for (int off = 1; off < 16; off <<= 1)
        mloc = fmaxf(mloc, __shfl_xor(mloc, off));
      float mold = mS[row];
      float mnew = fmaxf(mold, mloc);
      float al = __expf(mold - mnew);
      float psum = 0.f;
      #pragma unroll
      for (int j = 0; j < 4; ++j) {
        float p = __expf(sv[j] - mnew);
        psum += p;
        Ps[row * PROWP + l16 + 16 * j] = f2b(p);
      }
      #pragma unroll
      for (int off = 1; off < 16; off <<= 1)
        psum += __shfl_xor(psum, off);
      if (l16 == 0) {
        mS[row] = mnew;
        lS[row] = lS[row] * al + psum;
        aS[row] = al;
      }
    }
    asm volatile("s_waitcnt lgkmcnt(0)" ::: "memory");
    __builtin_amdgcn_s_barrier();

    // ---- rescale acc + PV: wave owns d-slice [wid*64, +64) ----
    {
      float alv[2][4];
      #pragma unroll
      for (int mi = 0; mi < 2; ++mi)
        #pragma unroll
        for (int r = 0; r < 4; ++r)
          alv[mi][r] = aS[mi * 16 + g4 * 4 + r];
      #pragma unroll
      for (int mi = 0; mi < 2; ++mi)
        #pragma unroll
        for (int ni = 0; ni < 4; ++ni)
          #pragma unroll
          for (int r = 0; r < 4; ++r)
            acc[mi][ni][r] *= alv[mi][r];

      const unsigned short* Bc = &Bs[cur][0];
      __builtin_amdgcn_s_setprio(1);
      #pragma unroll
      for (int ks = 0; ks < 2; ++ks) {
        bf16x8 pf[2];
        #pragma unroll
        for (int mi = 0; mi < 2; ++mi)
          pf[mi] = *reinterpret_cast<const bf16x8*>(
              &Ps[(mi * 16 + l16) * PROWP + ks * 32 + g4 * 8]);
        #pragma unroll
        for (int ni = 0; ni < 4; ++ni) {
          bf16x8 vv;
          #pragma unroll
          for (int j = 0; j < 8; ++j)
            vv[j] = (short)Bc[(ks * 8 + g4 * 2 + (j >> 2)) * ROWE
                              + (wid * 4 + ni) * 64 + (j & 3) * 16 + l16];
          #pragma unroll
          for (int mi = 0; mi < 2; ++mi)
            acc[mi][ni] = __builtin_amdgcn_mfma_f32_16x16x32_bf16(pf[mi], vv, acc[mi][ni], 0, 0, 0);
        }
      }
      __builtin_amdgcn_s_setprio(0);
    }
  }

  // ---- epilogue: out = acc / l + a ----
  float rl[2][4];
  #pragma unroll
  for (int mi = 0; mi < 2; ++mi)
    #pragma unroll
    for (int r = 0; r < 4; ++r)
      rl[mi][r] = 1.0f / lS[mi * 16 + g4 * 4 + r];
  #pragma unroll
  for (int mi = 0; mi < 2; ++mi)
    #pragma unroll
    for (int ni = 0; ni < 4; ++ni)
      #pragma unroll
      for (int r = 0; r < 4; ++r) {
        int q = qbase + mi * 16 + g4 * 4 + r;
        int d = wid * 64 + ni * 16 + l16;
        size_t off = (size_t)q * D + d;
        Ob[off] = acc[mi][ni][r] * rl[mi][r] + Ab[off];
      }
}

extern "C" void kernel_launch(void* const* d_in, const int* in_sizes, int n_in,
                              void* d_out, int out_size, void* d_ws, size_t ws_size,
                              hipStream_t stream) {
  const float* a = (const float*)d_in[0];
  const float* b = (const float*)d_in[1];
  float* out = (float*)d_out;
  const size_t need = (size_t)NB * NSEQ * D * sizeof(unsigned short);  // 16 MB
  dim3 grid(NB * (NSEQ / QBLK));
  dim3 block(NTHREADS);
  if (ws_size >= need) {
    unsigned short* b16 = (unsigned short*)d_ws;
    conv_b16<<<4096, 256, 0, stream>>>(b, b16);
    attn_fused<true><<<grid, block, 0, stream>>>(a, b, b16, out);
  } else {
    attn_fused<false><<<grid, block, 0, stream>>>(a, b, nullptr, out);
  }
}